// Round 7
// baseline (260.684 us; speedup 1.0000x reference)
//
#include <hip/hip_runtime.h>
#include <stdint.h>

#define N_NODES 207
#define N_EDGES 1722
#define N_SLOTS 288
#define L_DIM   64
#define NCSR    (2 * N_EDGES)   // 3444 CSR entries

// MFMA-path geometry: O^T[64 x 208] = xT[64 x 224] * lap[224 x 208]
#define NT_TILES 13              // N tiles of 16 (208)
#define KS_STEPS 7               // K steps of 32 (224)
#define TB_SLOT  (NT_TILES * KS_STEPS * 64 * 8)   // u16 elems per slot = 46,592 (93,184 B)
#define XSTRIDE  232             // xT LDS row stride in bf16 (16B-aligned frags, gcd-4 banks)

typedef __attribute__((ext_vector_type(8))) short bf16x8;   // 8 bf16 = 4 VGPRs
typedef __attribute__((ext_vector_type(4))) float f32x4;    // MFMA accumulator

// Round-to-nearest f32 -> bf16, returned as f32 bit pattern with low 16 zeroed
__device__ __forceinline__ unsigned int f2bf_rtn_bits_hi(float f) {
    unsigned int u = __float_as_uint(f);
    unsigned int r = u + 0x7FFFu + ((u >> 16) & 1u);
    return r & 0xFFFF0000u;
}

// ---------------------------------------------------------------------------
// K1 (fallback paths): build CSR from the batch-invariant edge list.
// ---------------------------------------------------------------------------
__global__ __launch_bounds__(256) void build_csr_kernel(
    const int* __restrict__ edge_i, const int* __restrict__ edge_j,
    int* __restrict__ row_start, unsigned int* __restrict__ csr_packed) {
    __shared__ int cnt[N_NODES];
    __shared__ int rs[N_NODES + 1];
    const int tid = threadIdx.x;

    for (int n = tid; n < N_NODES; n += 256) cnt[n] = 0;
    __syncthreads();
    for (int e = tid; e < N_EDGES; e += 256) {
        atomicAdd(&cnt[edge_i[e]], 1);
        atomicAdd(&cnt[edge_j[e]], 1);
    }
    __syncthreads();
    if (tid == 0) {
        int acc = 0;
        for (int n = 0; n < N_NODES; ++n) { rs[n] = acc; acc += cnt[n]; }
        rs[N_NODES] = acc;
    }
    __syncthreads();
    for (int n = tid; n <= N_NODES; n += 256) row_start[n] = rs[n];
    for (int n = tid; n < N_NODES; n += 256) cnt[n] = rs[n];
    __syncthreads();
    for (int e = tid; e < N_EDGES; e += 256) {
        const unsigned int i = edge_i[e], j = edge_j[e];
        const unsigned int ep = ((unsigned int)e) << 8;
        int p = atomicAdd(&cnt[i], 1);
        csr_packed[p] = ep | j;
        int q = atomicAdd(&cnt[j], 1);
        csr_packed[q] = ep | i;
    }
}

// ---------------------------------------------------------------------------
// K1b (fallback paths): per-slot coef {1+wsl+deg, bias} + packed edge stream.
// ---------------------------------------------------------------------------
__global__ __launch_bounds__(256) void coef_eb_kernel(
    const float* __restrict__ weight_diff, const float* __restrict__ bias_diffusion,
    const float* __restrict__ weight_self_loop,
    const int* __restrict__ row_start, const unsigned int* __restrict__ csr_packed,
    float2* __restrict__ coefbias, unsigned int* __restrict__ eb32) {
    __shared__ float wrow[N_EDGES];
    const int s = blockIdx.x;
    for (int e = threadIdx.x; e < N_EDGES; e += 256)
        wrow[e] = weight_diff[(size_t)s * N_EDGES + e];
    __syncthreads();

    if (eb32 != nullptr) {
        unsigned int* ebs = eb32 + (size_t)s * NCSR;
        for (int k = threadIdx.x; k < NCSR; k += 256) {
            const unsigned int c = csr_packed[k];
            ebs[k] = f2bf_rtn_bits_hi(wrow[c >> 8]) | ((c & 255u) << 7);
        }
    }

    const int n = threadIdx.x;
    if (n < N_NODES) {
        float d = 0.f;
        const int e0 = row_start[n], e1 = row_start[n + 1];
        for (int k = e0; k < e1; ++k) d += wrow[csr_packed[k] >> 8];
        coefbias[s * N_NODES + n] = make_float2(
            1.f + weight_self_loop[s * N_NODES + n] + d,
            bias_diffusion[s * N_NODES + n]);
    }
}

// ---------------------------------------------------------------------------
// MFMA precompute (unchanged from round 6, verified): dense lap = deg*I - A,
// 32 k-rows per chunk, bf16 pre-swizzled into MFMA B-fragment order:
//   tableB[s][nt][ks][lane][j] = lap[ks*32+(lane>>4)*8+j][nt*16+(lane&15)]
// coefbias_m[s][n] = {1 + wsl, bias} (deg lives inside lap diag).
// ---------------------------------------------------------------------------
__global__ __launch_bounds__(256) void lap_table_kernel(
    const float* __restrict__ weight_diff, const float* __restrict__ bias_diffusion,
    const float* __restrict__ weight_self_loop,
    const int* __restrict__ edge_i, const int* __restrict__ edge_j,
    unsigned short* __restrict__ tableB, float2* __restrict__ coefbias) {
    __shared__ float wrow[N_EDGES];        //  6,888 B
    __shared__ int   ei[N_EDGES];          //  6,888 B
    __shared__ int   ej[N_EDGES];          //  6,888 B
    __shared__ float lapc[32][228];        // 29,184 B
    const int s = blockIdx.x, t = threadIdx.x;

    for (int e = t; e < N_EDGES; e += 256) {
        wrow[e] = weight_diff[(size_t)s * N_EDGES + e];
        ei[e] = edge_i[e];
        ej[e] = edge_j[e];
    }
    if (t < N_NODES) {
        coefbias[s * N_NODES + t] = make_float2(
            1.f + weight_self_loop[s * N_NODES + t],
            bias_diffusion[s * N_NODES + t]);
    }
    __syncthreads();

    unsigned int* outp = (unsigned int*)(tableB + (size_t)s * TB_SLOT);

    for (int c = 0; c < KS_STEPS; ++c) {   // k-rows [32c, 32c+32), ks = c
        const int r0 = c * 32;
        for (int k = t; k < (32 * 228) / 4; k += 256)
            ((float4*)&lapc[0][0])[k] = make_float4(0.f, 0.f, 0.f, 0.f);
        __syncthreads();
        for (int e = t; e < N_EDGES; e += 256) {
            const int i = ei[e], j = ej[e];
            const float w = wrow[e];
            if ((unsigned)(i - r0) < 32u) {
                atomicAdd(&lapc[i - r0][j], -w);
                atomicAdd(&lapc[i - r0][i],  w);
            }
            if ((unsigned)(j - r0) < 32u) {
                atomicAdd(&lapc[j - r0][i], -w);
                atomicAdd(&lapc[j - r0][j],  w);
            }
        }
        __syncthreads();
        const int ln = t >> 2;               // fragment lane 0..63
        const int jp = (t & 3) << 1;         // j = jp, jp+1
        const int kl = ((ln >> 4) << 3) + jp;
        for (int nt = 0; nt < NT_TILES; ++nt) {
            const int n = nt * 16 + (ln & 15);
            const unsigned u0 = f2bf_rtn_bits_hi(lapc[kl][n]) >> 16;
            const unsigned u1 = f2bf_rtn_bits_hi(lapc[kl + 1][n]);
            outp[((nt * KS_STEPS + c) * 64 + ln) * 4 + (jp >> 1)] = u0 | u1;
        }
        __syncthreads();
    }
}

// ---------------------------------------------------------------------------
// K2 (MFMA v2): one block (512 thr = 8 waves) per batch element.
// O^T[l][n] = sum_k xT[l][k] * lap[k][n]; epilogue via PER-WAVE LDS scratch
// transpose so global writes are 1KB-contiguous (4 full 256B rows / inst),
// fixing round-6's 2x write amplification (WRITE_SIZE 104MB for 54MB output:
// 16 rows x 64B chunks per store inst failed to merge into 128B lines).
// x re-read + coefbias read moved into the same loop at identical addresses
// -> fully coalesced. Scratch is wave-private: NO barriers.
// LDS: xT 29,696 + scratch 8*16*68*4 = 34,816 -> 64,512 B -> 2 blocks/CU.
// ---------------------------------------------------------------------------
__global__ __launch_bounds__(512, 4) void diffusion_mfma_kernel(
    const float* __restrict__ inputs,             // (B, 2, 207, 64)
    const int*   __restrict__ ind,                // (B,)
    const unsigned short* __restrict__ tableB,    // (288, TB_SLOT)
    const float2* __restrict__ coefbias,          // (288, 207) = {1+wsl, bias}
    float* __restrict__ out) {                    // (B, 207, 64)
    __shared__ unsigned short xT[64 * XSTRIDE];   // 29,696 B
    __shared__ float scratch[8][16][68];          // 34,816 B (stride 68: b128-aligned)

    const int b    = blockIdx.x;
    const int tid  = threadIdx.x;
    const int slot = ind[b];
    const float* xb = inputs + (size_t)b * (2 * N_NODES * L_DIM);  // channel 0

    // zero xT (covers K-pad cols 207..223 read by A-frags)
    for (int k = tid; k < (64 * XSTRIDE * 2) / 16; k += 512)
        ((uint4*)xT)[k] = make_uint4(0u, 0u, 0u, 0u);
    __syncthreads();

    // transpose-fill: x[v][l] (fp32) -> xT[l][v] (bf16)
    const float4* xb4 = (const float4*)xb;
    for (int idx = tid; idx < (N_NODES * L_DIM) / 4; idx += 512) {
        const int v  = idx >> 4;
        const int l0 = (idx & 15) << 2;
        const float4 q = xb4[idx];
        xT[(l0 + 0) * XSTRIDE + v] = (unsigned short)(f2bf_rtn_bits_hi(q.x) >> 16);
        xT[(l0 + 1) * XSTRIDE + v] = (unsigned short)(f2bf_rtn_bits_hi(q.y) >> 16);
        xT[(l0 + 2) * XSTRIDE + v] = (unsigned short)(f2bf_rtn_bits_hi(q.z) >> 16);
        xT[(l0 + 3) * XSTRIDE + v] = (unsigned short)(f2bf_rtn_bits_hi(q.w) >> 16);
    }
    __syncthreads();

    const int lane = tid & 63;
    const int wv   = tid >> 6;
    const int ra   = lane & 15;           // A row (within M-tile) / D col (n-local)
    const int g    = lane >> 4;           // quad index
    const int kq   = g << 3;              // A k-offset within K-step
    float* ob = out + (size_t)b * (N_NODES * L_DIM);
    const unsigned short* tbs = tableB + (size_t)slot * TB_SLOT;
    const float2* cbs = coefbias + (size_t)slot * N_NODES;
    float (*sw)[68] = scratch[wv];        // wave-private [16][68]

    for (int nt = wv; nt < NT_TILES; nt += 8) {
        f32x4 acc0 = {0.f, 0.f, 0.f, 0.f};
        f32x4 acc1 = {0.f, 0.f, 0.f, 0.f};
        f32x4 acc2 = {0.f, 0.f, 0.f, 0.f};
        f32x4 acc3 = {0.f, 0.f, 0.f, 0.f};
        const unsigned short* tbn = tbs + nt * (KS_STEPS * 512) + lane * 8;
        #pragma unroll
        for (int ks = 0; ks < KS_STEPS; ++ks) {
            const bf16x8 bb = *(const bf16x8*)(tbn + ks * 512);
            const int kof = ks * 32 + kq;
            const bf16x8 a0 = *(const bf16x8*)&xT[(ra     ) * XSTRIDE + kof];
            const bf16x8 a1 = *(const bf16x8*)&xT[(ra + 16) * XSTRIDE + kof];
            const bf16x8 a2 = *(const bf16x8*)&xT[(ra + 32) * XSTRIDE + kof];
            const bf16x8 a3 = *(const bf16x8*)&xT[(ra + 48) * XSTRIDE + kof];
            acc0 = __builtin_amdgcn_mfma_f32_16x16x32_bf16(a0, bb, acc0, 0, 0, 0);
            acc1 = __builtin_amdgcn_mfma_f32_16x16x32_bf16(a1, bb, acc1, 0, 0, 0);
            acc2 = __builtin_amdgcn_mfma_f32_16x16x32_bf16(a2, bb, acc2, 0, 0, 0);
            acc3 = __builtin_amdgcn_mfma_f32_16x16x32_bf16(a3, bb, acc3, 0, 0, 0);
        }
        // --- scratch transpose: acc[MT][j] = OT[l = MT*16 + g*4 + j][n-local ra]
        //     write as [n-local][l] so readback rows are contiguous in l.
        *(f32x4*)&sw[ra][ 0 + (g << 2)] = acc0;
        *(f32x4*)&sw[ra][16 + (g << 2)] = acc1;
        *(f32x4*)&sw[ra][32 + (g << 2)] = acc2;
        *(f32x4*)&sw[ra][48 + (g << 2)] = acc3;
        // --- readback + fused epilogue, 1KB-contiguous global access:
        //     inst covers 4 rows x 256B (n = nt*16 + it2*4 + g, l = (lane&15)*4)
        #pragma unroll
        for (int it2 = 0; it2 < 4; ++it2) {
            const int nl = (it2 << 2) + g;
            const int n  = nt * 16 + nl;
            if (n < N_NODES) {
                const int l4 = ra << 2;
                const f32x4 ot = *(const f32x4*)&sw[nl][l4];
                const float2 cb = cbs[n];
                const float4 xg = *(const float4*)(xb + (n << 6) + l4);
                float4 o;
                o.x = fmaf(cb.x, xg.x, ot[0] + cb.y);
                o.y = fmaf(cb.x, xg.y, ot[1] + cb.y);
                o.z = fmaf(cb.x, xg.z, ot[2] + cb.y);
                o.w = fmaf(cb.x, xg.w, ot[3] + cb.y);
                *(float4*)(ob + (n << 6) + l4) = o;
            }
        }
    }
}

// ---------------------------------------------------------------------------
// K2 (tier-2 fallback, round-4 verified, 70.6 us): precomputed edge stream.
// ---------------------------------------------------------------------------
__global__ __launch_bounds__(512, 8) void diffusion_lds_kernel(
    const float* __restrict__ inputs,
    const int*   __restrict__ ind,
    const int*   __restrict__ row_start,
    const unsigned int* __restrict__ eb32,
    const float2* __restrict__ coefbias,
    float* __restrict__ out) {
    __shared__ unsigned short xs[N_NODES * L_DIM];
    __shared__ unsigned int   wnb[NCSR];
    __shared__ unsigned short rs[N_NODES + 1];

    const int b    = blockIdx.x;
    const int tid  = threadIdx.x;
    const int slot = ind[b];

    const float* xb = inputs + (size_t)b * (2 * N_NODES * L_DIM);

    const float4* xb4 = (const float4*)xb;
    for (int k = tid; k < (N_NODES * L_DIM) / 4; k += 512) {
        const float4 v = xb4[k];
        const unsigned int lo = (f2bf_rtn_bits_hi(v.x) >> 16) | f2bf_rtn_bits_hi(v.y);
        const unsigned int hi = (f2bf_rtn_bits_hi(v.z) >> 16) | f2bf_rtn_bits_hi(v.w);
        ((uint2*)xs)[k] = make_uint2(lo, hi);
    }
    {
        const uint4* src = (const uint4*)(eb32 + (size_t)slot * NCSR);
        uint4* dst = (uint4*)wnb;
        for (int k = tid; k < NCSR / 4; k += 512) dst[k] = src[k];
    }
    for (int n = tid; n <= N_NODES; n += 512) rs[n] = (unsigned short)row_start[n];
    __syncthreads();

    const int lane  = tid & 63;
    const unsigned int lane2 = (unsigned int)(lane << 1);
    const int wv    = tid >> 6;
    float* ob = out + (size_t)b * (N_NODES * L_DIM);
    const char* xsb = (const char*)xs;
    const float2* cbs = coefbias + (size_t)slot * N_NODES;

    for (int n = wv; n < N_NODES; n += 8) {
        const int e0 = rs[n], e1 = rs[n + 1];
        float s = 0.f;
        #pragma unroll 4
        for (int k = e0; k < e1; ++k) {
            const unsigned int p = wnb[k];
            const float w = __uint_as_float(p & 0xFFFF0000u);
            const unsigned int off = (p & 0xFFFFu) | lane2;
            const unsigned int xv = *(const unsigned short*)(xsb + off);
            s = fmaf(w, __uint_as_float(xv << 16), s);
        }
        const float2 cb = cbs[n];
        const float  xg = xb[(n << 6) + lane];
        ob[(n << 6) + lane] = fmaf(cb.x, xg, cb.y) - s;
    }
}

// ---------------------------------------------------------------------------
// K2 (tier-3 fallback, original 237.9 us baseline): per-block weight gather.
// ---------------------------------------------------------------------------
__global__ __launch_bounds__(512, 8) void diffusion_gcn_fallback(
    const float* __restrict__ inputs,
    const float* __restrict__ weight_diff,
    const int*   __restrict__ ind,
    const int*   __restrict__ row_start,
    const unsigned int* __restrict__ csr_packed,
    const float2* __restrict__ coefbias,
    float* __restrict__ out) {
    __shared__ unsigned short xsh[N_NODES * L_DIM];
    __shared__ unsigned int   wnb[NCSR];
    __shared__ unsigned short rs[N_NODES + 1];

    const int b    = blockIdx.x;
    const int tid  = threadIdx.x;
    const int slot = ind[b];

    const float* xb = inputs + (size_t)b * (2 * N_NODES * L_DIM);

    const float4* xb4 = (const float4*)xb;
    for (int k = tid; k < (N_NODES * L_DIM) / 4; k += 512) {
        const float4 v = xb4[k];
        const unsigned int lo = (f2bf_rtn_bits_hi(v.x) >> 16) | f2bf_rtn_bits_hi(v.y);
        const unsigned int hi = (f2bf_rtn_bits_hi(v.z) >> 16) | f2bf_rtn_bits_hi(v.w);
        ((uint2*)xsh)[k] = make_uint2(lo, hi);
    }
    const float* wrow = weight_diff + (size_t)slot * N_EDGES;
    for (int k = tid; k < NCSR; k += 512) {
        const unsigned int c = csr_packed[k];
        wnb[k] = f2bf_rtn_bits_hi(wrow[c >> 8]) | (c & 255u);
    }
    for (int n = tid; n <= N_NODES; n += 512) rs[n] = (unsigned short)row_start[n];
    __syncthreads();

    const int lane = tid & 63;
    const int wv   = tid >> 6;
    float* ob = out + (size_t)b * (N_NODES * L_DIM);

    for (int n = wv; n < N_NODES; n += 8) {
        const int e0 = rs[n], e1 = rs[n + 1];
        float s = 0.f;
        #pragma unroll 4
        for (int k = e0; k < e1; ++k) {
            const unsigned int p = wnb[k];
            const float w  = __uint_as_float(p & 0xFFFF0000u);
            const float xv = __uint_as_float(
                (unsigned int)xsh[(p & 255u) * L_DIM + lane] << 16);
            s = fmaf(w, xv, s);
        }
        const float2 cb = coefbias[slot * N_NODES + n];
        const float  xg = xb[n * L_DIM + lane];
        ob[n * L_DIM + lane] = fmaf(cb.x, xg, cb.y) - s;
    }
}

extern "C" void kernel_launch(void* const* d_in, const int* in_sizes, int n_in,
                              void* d_out, int out_size, void* d_ws, size_t ws_size,
                              hipStream_t stream) {
    const float* inputs           = (const float*)d_in[0];
    const float* weight_diff      = (const float*)d_in[1];
    const float* bias_diffusion   = (const float*)d_in[2];
    const float* weight_self_loop = (const float*)d_in[3];
    const int*   ind              = (const int*)d_in[4];
    const int*   edge_i           = (const int*)d_in[5];
    const int*   edge_j           = (const int*)d_in[6];
    float* out = (float*)d_out;

    const int B = in_sizes[4];                 // 1024

    char* ws = (char*)d_ws;

    // --- tier 1: MFMA layout ---
    unsigned short* tableB     = (unsigned short*)ws;                 // 26,836,992 B
    float2*         coefbias_m = (float2*)(ws + 26836992);            //    476,928 B
    const size_t WS_MFMA = 26836992 + (size_t)N_SLOTS * N_NODES * sizeof(float2);

    // --- tier 2/3: CSR layout ---
    int*          row_start  = (int*)ws;                              //     832 B
    unsigned int* csr_packed = (unsigned int*)(ws + 832);             //  13,776 B
    float2*       coefbias   = (float2*)(ws + 14608);                 // 476,928 B
    unsigned int* eb32       = (unsigned int*)(ws + 491536);          // 3,967,488 B
    const size_t WS_EB  = 491536 + (size_t)N_SLOTS * NCSR * sizeof(unsigned int);

    if (d_ws != nullptr && ws_size >= WS_MFMA) {
        lap_table_kernel<<<N_SLOTS, 256, 0, stream>>>(
            weight_diff, bias_diffusion, weight_self_loop, edge_i, edge_j,
            tableB, coefbias_m);
        diffusion_mfma_kernel<<<B, 512, 0, stream>>>(
            inputs, ind, tableB, coefbias_m, out);
    } else if (d_ws != nullptr && ws_size >= WS_EB) {
        build_csr_kernel<<<1, 256, 0, stream>>>(edge_i, edge_j, row_start, csr_packed);
        coef_eb_kernel<<<N_SLOTS, 256, 0, stream>>>(
            weight_diff, bias_diffusion, weight_self_loop, row_start, csr_packed,
            coefbias, eb32);
        diffusion_lds_kernel<<<B, 512, 0, stream>>>(
            inputs, ind, row_start, eb32, coefbias, out);
    } else {
        build_csr_kernel<<<1, 256, 0, stream>>>(edge_i, edge_j, row_start, csr_packed);
        coef_eb_kernel<<<N_SLOTS, 256, 0, stream>>>(
            weight_diff, bias_diffusion, weight_self_loop, row_start, csr_packed,
            coefbias, nullptr);
        diffusion_gcn_fallback<<<B, 512, 0, stream>>>(
            inputs, weight_diff, ind, row_start, csr_packed, coefbias, out);
    }
}

// Round 8
// 238.415 us; speedup vs baseline: 1.0934x; 1.0934x over previous
//
#include <hip/hip_runtime.h>
#include <stdint.h>

#define N_NODES 207
#define N_EDGES 1722
#define N_SLOTS 288
#define L_DIM   64
#define EB_STRIDE 4096   // padded CSR capacity: max 3444 + 3*207 = 4065 <= 4096

// Round-to-nearest f32 -> bf16, returned as f32 bit pattern with low 16 zeroed
__device__ __forceinline__ unsigned int f2bf_rtn_bits_hi(float f) {
    unsigned int u = __float_as_uint(f);
    unsigned int r = u + 0x7FFFu + ((u >> 16) & 1u);
    return r & 0xFFFF0000u;
}

// ---------------------------------------------------------------------------
// K1: build PADDED CSR from the batch-invariant edge list.
//   rs_p[208] ints (each node's segment padded to a multiple of 4)
//   csr_p[4096] uints = (edge_id<<8)|neighbor, pad slots = 0xFFFFFFFF
// Self-loop edges (i==j) appear twice in node i's list -> A[i,i] += 2w (matches ref).
// ---------------------------------------------------------------------------
__global__ __launch_bounds__(256) void build_csr_kernel(
    const int* __restrict__ edge_i, const int* __restrict__ edge_j,
    int* __restrict__ rs_p, unsigned int* __restrict__ csr_p) {
    __shared__ int cnt[N_NODES];
    __shared__ int rs[N_NODES + 1];
    const int tid = threadIdx.x;

    for (int n = tid; n < N_NODES; n += 256) cnt[n] = 0;
    __syncthreads();
    for (int e = tid; e < N_EDGES; e += 256) {
        atomicAdd(&cnt[edge_i[e]], 1);
        atomicAdd(&cnt[edge_j[e]], 1);
    }
    __syncthreads();
    if (tid == 0) {
        int acc = 0;
        for (int n = 0; n < N_NODES; ++n) { rs[n] = acc; acc += (cnt[n] + 3) & ~3; }
        rs[N_NODES] = acc;   // <= 4065
    }
    __syncthreads();
    for (int n = tid; n <= N_NODES; n += 256) rs_p[n] = rs[n];
    for (int k = tid; k < EB_STRIDE; k += 256) csr_p[k] = 0xFFFFFFFFu;  // pads
    for (int n = tid; n < N_NODES; n += 256) cnt[n] = rs[n];
    __syncthreads();   // orders the global pad-fill before the scatter (same block)
    for (int e = tid; e < N_EDGES; e += 256) {
        const unsigned int i = edge_i[e], j = edge_j[e];
        const unsigned int ep = ((unsigned int)e) << 8;
        int p = atomicAdd(&cnt[i], 1);
        csr_p[p] = ep | j;
        int q = atomicAdd(&cnt[j], 1);
        csr_p[q] = ep | i;
    }
}

// ---------------------------------------------------------------------------
// K1b: per slot, precompute
//   coefbias[s][n] = {1 + wsl + deg, bias}                  (float2)
//   eb32p[s][k]    = (w bf16 in HIGH16) | (nb*128 in LOW16) (u32; pads = 0)
// K2 streams eb32p from GLOBAL (L2-hot, 16 KB/slot) -- keeps the LDS pipe free
// for the x-gather, which round-4 analysis showed is the binding resource.
// ---------------------------------------------------------------------------
__global__ __launch_bounds__(256) void coef_eb_kernel(
    const float* __restrict__ weight_diff, const float* __restrict__ bias_diffusion,
    const float* __restrict__ weight_self_loop,
    const int* __restrict__ rs_p, const unsigned int* __restrict__ csr_p,
    float2* __restrict__ coefbias, unsigned int* __restrict__ eb32p) {
    __shared__ float wrow[N_EDGES];
    const int s = blockIdx.x;
    for (int e = threadIdx.x; e < N_EDGES; e += 256)
        wrow[e] = weight_diff[(size_t)s * N_EDGES + e];
    __syncthreads();

    if (eb32p != nullptr) {
        const int EP = rs_p[N_NODES];
        unsigned int* ebs = eb32p + (size_t)s * EB_STRIDE;
        for (int k = threadIdx.x; k < EB_STRIDE; k += 256) {
            unsigned int v = 0u;
            if (k < EP) {
                const unsigned int c = csr_p[k];
                if (c != 0xFFFFFFFFu)
                    v = f2bf_rtn_bits_hi(wrow[c >> 8]) | ((c & 255u) << 7);
            }
            ebs[k] = v;
        }
    }

    const int n = threadIdx.x;
    if (n < N_NODES) {
        float d = 0.f;
        const int e0 = rs_p[n], e1 = rs_p[n + 1];
        for (int k = e0; k < e1; ++k) {
            const unsigned int c = csr_p[k];
            if (c != 0xFFFFFFFFu) d += wrow[c >> 8];
        }
        coefbias[s * N_NODES + n] = make_float2(
            1.f + weight_self_loop[s * N_NODES + n] + d,
            bias_diffusion[s * N_NODES + n]);
    }
}

// ---------------------------------------------------------------------------
// K2 (quad-edge): one block (512 thr = 8 waves) per batch element.
//   out[n,l] = coef*x[n,l] + bias - sum_k w[k]*x[nb[k],l]
// Round-4 post-mortem: 2 LDS reads/edge x 5.8cyc x 4 blocks = 66us ~= measured
// 70.6us -> LDS-PIPE bound. This kernel cuts LDS to 0.25 insts/edge:
//  - edge stream p read from GLOBAL (separate VMEM pipe; 4 distinct addrs/wave,
//    broadcast-coalesced; slot stream 16KB = L2-resident)
//  - x-gather widened to ds_read_b64: lane covers l=4i..4i+3; the wave's 4
//    quads (h=lane>>4) process edges k..k+3 simultaneously (lists padded to 4)
//  - per-node 2x shfl_xor reduction; 16-lane float4 epilogue (exact writes)
// LDS = 26,496 + 828 = 27.3 KB -> 4 blocks/CU, 32 waves/CU.
// ---------------------------------------------------------------------------
__global__ __launch_bounds__(512, 8) void diffusion_quad_kernel(
    const float* __restrict__ inputs,          // (B, 2, 207, 64)
    const int*   __restrict__ ind,             // (B,)
    const int*   __restrict__ rs_p_g,          // (208,) padded
    const unsigned int* __restrict__ eb32p,    // (288, EB_STRIDE)
    const float2* __restrict__ coefbias,       // (288, 207)
    float* __restrict__ out) {                 // (B, 207, 64)
    __shared__ unsigned short xs[N_NODES * L_DIM];   // 26,496 B (bf16, row = 128 B)
    __shared__ unsigned int   rsp[N_NODES];          //    828 B: e0 | e1<<16

    const int b    = blockIdx.x;
    const int tid  = threadIdx.x;
    const int slot = ind[b];                   // uniform -> SGPR

    const float* xb = inputs + (size_t)b * (2 * N_NODES * L_DIM);  // channel 0

    // Stage x (fp32 global, float4) -> bf16 LDS (linear rows)
    const float4* xb4 = (const float4*)xb;
    for (int k = tid; k < (N_NODES * L_DIM) / 4; k += 512) {
        const float4 v = xb4[k];
        const unsigned int lo = (f2bf_rtn_bits_hi(v.x) >> 16) | f2bf_rtn_bits_hi(v.y);
        const unsigned int hi = (f2bf_rtn_bits_hi(v.z) >> 16) | f2bf_rtn_bits_hi(v.w);
        ((uint2*)xs)[k] = make_uint2(lo, hi);
    }
    for (int n = tid; n < N_NODES; n += 512)
        rsp[n] = (unsigned int)rs_p_g[n] | ((unsigned int)rs_p_g[n + 1] << 16);
    __syncthreads();

    const int lane = tid & 63;
    const int wv   = tid >> 6;                 // 8 waves
    const int h    = lane >> 4;                // quad 0..3 -> edge k+h
    const unsigned int li8 = (unsigned int)((lane & 15) << 3);  // byte off: l=4i
    const unsigned int* ebs = eb32p + (size_t)slot * EB_STRIDE;
    const float2* cbs = coefbias + (size_t)slot * N_NODES;
    float* ob = out + (size_t)b * (N_NODES * L_DIM);
    const char* xsb = (const char*)xs;

    for (int n = wv; n < N_NODES; n += 8) {
        const unsigned int rr = rsp[n];        // one ds_read_b32 per node
        const int e0 = (int)(rr & 0xFFFFu);
        const int e1 = (int)(rr >> 16);
        float s0 = 0.f, s1 = 0.f, s2 = 0.f, s3 = 0.f;
        #pragma unroll 2
        for (int k = e0; k < e1; k += 4) {     // (e1-e0) is a multiple of 4
            const unsigned int p = ebs[k + h];                 // global, L2-hot
            const unsigned int w = p & 0xFFFF0000u;            // bf16 weight bits
            const unsigned int off = (p & 0xFFFFu) | li8;      // nb*128 | i*8
            const uint2 xv = *(const uint2*)(xsb + off);       // ds_read_b64
            s0 = fmaf(__uint_as_float(w), __uint_as_float(xv.x << 16), s0);
            s1 = fmaf(__uint_as_float(w), __uint_as_float(xv.x & 0xFFFF0000u), s1);
            s2 = fmaf(__uint_as_float(w), __uint_as_float(xv.y << 16), s2);
            s3 = fmaf(__uint_as_float(w), __uint_as_float(xv.y & 0xFFFF0000u), s3);
        }
        // combine the 4 quads' partial sums (each quad summed edges k+h, h=0..3)
        s0 += __shfl_xor(s0, 16); s1 += __shfl_xor(s1, 16);
        s2 += __shfl_xor(s2, 16); s3 += __shfl_xor(s3, 16);
        s0 += __shfl_xor(s0, 32); s1 += __shfl_xor(s1, 32);
        s2 += __shfl_xor(s2, 32); s3 += __shfl_xor(s3, 32);
        if (lane < 16) {                       // 16 lanes x float4 = exact 256B row
            const float2 cb = cbs[n];
            const int o4 = (n << 6) + (lane << 2);
            const float4 xg = *(const float4*)(xb + o4);   // fp32 self term
            float4 o;
            o.x = fmaf(cb.x, xg.x, cb.y) - s0;
            o.y = fmaf(cb.x, xg.y, cb.y) - s1;
            o.z = fmaf(cb.x, xg.z, cb.y) - s2;
            o.w = fmaf(cb.x, xg.w, cb.y) - s3;
            *(float4*)(ob + o4) = o;
        }
    }
}

// ---------------------------------------------------------------------------
// K2 (fallback, baseline-style, padded-CSR aware): used only if ws too small
// for the eb32p table. Per-block weight gather + u16 LDS reads.
// ---------------------------------------------------------------------------
__global__ __launch_bounds__(512, 8) void diffusion_gcn_fallback(
    const float* __restrict__ inputs,
    const float* __restrict__ weight_diff,
    const int*   __restrict__ ind,
    const int*   __restrict__ rs_p_g,
    const unsigned int* __restrict__ csr_p,
    const float2* __restrict__ coefbias,
    float* __restrict__ out) {
    __shared__ unsigned short xsh[N_NODES * L_DIM];
    __shared__ unsigned int   wnb[EB_STRIDE];
    __shared__ unsigned short rs[N_NODES + 1];

    const int b    = blockIdx.x;
    const int tid  = threadIdx.x;
    const int slot = ind[b];

    const float* xb = inputs + (size_t)b * (2 * N_NODES * L_DIM);

    const float4* xb4 = (const float4*)xb;
    for (int k = tid; k < (N_NODES * L_DIM) / 4; k += 512) {
        const float4 v = xb4[k];
        const unsigned int lo = (f2bf_rtn_bits_hi(v.x) >> 16) | f2bf_rtn_bits_hi(v.y);
        const unsigned int hi = (f2bf_rtn_bits_hi(v.z) >> 16) | f2bf_rtn_bits_hi(v.w);
        ((uint2*)xsh)[k] = make_uint2(lo, hi);
    }
    const int EP = rs_p_g[N_NODES];
    const float* wrow = weight_diff + (size_t)slot * N_EDGES;
    for (int k = tid; k < EP; k += 512) {
        const unsigned int c = csr_p[k];
        wnb[k] = (c == 0xFFFFFFFFu) ? 0u
                                    : (f2bf_rtn_bits_hi(wrow[c >> 8]) | (c & 255u));
    }
    for (int n = tid; n <= N_NODES; n += 512) rs[n] = (unsigned short)rs_p_g[n];
    __syncthreads();

    const int lane = tid & 63;
    const int wv   = tid >> 6;
    float* ob = out + (size_t)b * (N_NODES * L_DIM);

    for (int n = wv; n < N_NODES; n += 8) {
        const int e0 = rs[n], e1 = rs[n + 1];
        float s = 0.f;
        #pragma unroll 4
        for (int k = e0; k < e1; ++k) {
            const unsigned int p = wnb[k];
            const float w  = __uint_as_float(p & 0xFFFF0000u);
            const float xv = __uint_as_float(
                (unsigned int)xsh[(p & 255u) * L_DIM + lane] << 16);
            s = fmaf(w, xv, s);
        }
        const float2 cb = coefbias[slot * N_NODES + n];
        const float  xg = xb[n * L_DIM + lane];
        ob[n * L_DIM + lane] = fmaf(cb.x, xg, cb.y) - s;
    }
}

extern "C" void kernel_launch(void* const* d_in, const int* in_sizes, int n_in,
                              void* d_out, int out_size, void* d_ws, size_t ws_size,
                              hipStream_t stream) {
    const float* inputs           = (const float*)d_in[0];
    const float* weight_diff      = (const float*)d_in[1];
    const float* bias_diffusion   = (const float*)d_in[2];
    const float* weight_self_loop = (const float*)d_in[3];
    const int*   ind              = (const int*)d_in[4];
    const int*   edge_i           = (const int*)d_in[5];
    const int*   edge_j           = (const int*)d_in[6];
    float* out = (float*)d_out;

    const int B = in_sizes[4];                 // 1024

    // ws layout
    char* ws = (char*)d_ws;
    int*          rs_p     = (int*)ws;                           //      1,024 B
    unsigned int* csr_p    = (unsigned int*)(ws + 1024);         //     16,384 B
    float2*       coefbias = (float2*)(ws + 17408);              //    476,928 B
    unsigned int* eb32p    = (unsigned int*)(ws + 494336);       //  4,718,592 B
    const size_t WS_FULL = 494336 + (size_t)N_SLOTS * EB_STRIDE * sizeof(unsigned int);

    const bool full = (d_ws != nullptr) && (ws_size >= WS_FULL);

    build_csr_kernel<<<1, 256, 0, stream>>>(edge_i, edge_j, rs_p, csr_p);
    coef_eb_kernel<<<N_SLOTS, 256, 0, stream>>>(
        weight_diff, bias_diffusion, weight_self_loop, rs_p, csr_p,
        coefbias, full ? eb32p : nullptr);
    if (full) {
        diffusion_quad_kernel<<<B, 512, 0, stream>>>(
            inputs, ind, rs_p, eb32p, coefbias, out);
    } else {
        diffusion_gcn_fallback<<<B, 512, 0, stream>>>(
            inputs, weight_diff, ind, rs_p, csr_p, coefbias, out);
    }
}